// Round 5
// baseline (71.110 us; speedup 1.0000x reference)
//
#include <hip/hip_runtime.h>

typedef __attribute__((ext_vector_type(8))) __bf16 bf16x8;
typedef __attribute__((ext_vector_type(4))) __bf16 bf16x4;
typedef __attribute__((ext_vector_type(4))) float f32x4;

__device__ __forceinline__ __bf16 f2bf(float f) { return (__bf16)f; }
__device__ __forceinline__ f32x4 ld4(const float* p) { return *(const f32x4*)p; }

#define WBF_ELEMS 18432
#define X_OFF_BYTES 36864           // after wbf (18432 bf16)
#define AT 32                        // elements per block in gather kernel

// One-time: convert w1 (64x192) and w2 (96x64) f32 -> bf16 into ws.
__global__ void prep_weights(const float* __restrict__ w1, const float* __restrict__ w2,
                             __bf16* __restrict__ wbf) {
    const int i = blockIdx.x * 256 + threadIdx.x;
    if (i < 12288)       wbf[i] = f2bf(w1[i]);
    else if (i < 18432)  wbf[i] = f2bf(w2[i - 12288]);
}

// =================== Kernel A: gather + GMF partial ===================
// 8 lanes per element; 32 elements per 256-thread block. Register-lean.
// IDEMPOTENT: launched twice in round 5 to measure its steady-state cost
// as (dur_r5 - dur_r4).
__global__ __launch_bounds__(256, 8)
void ncf_gather(const int* __restrict__ user_ids, const int* __restrict__ movie_ids,
                const int* __restrict__ genre_ids, const int* __restrict__ offsets,
                const float* __restrict__ user_mem_w, const float* __restrict__ movie_mem_w,
                const float* __restrict__ ue_gmf, const float* __restrict__ me_gmf,
                const float* __restrict__ ge_gmf,
                const float* __restrict__ ue_mlp, const float* __restrict__ me_mlp,
                const float* __restrict__ ge_mlp,
                const float* __restrict__ w_out, const float* __restrict__ b_out,
                __bf16* __restrict__ X, float* __restrict__ pv, int Btot, int totG)
{
    const int tid  = threadIdx.x;
    const int c    = tid & 7;                 // 8 lanes per element
    const int el   = tid >> 3;                // 0..31
    const int gidx = min(blockIdx.x * AT + el, Btot - 1);

    const int u    = user_ids[gidx];
    const int mv   = movie_ids[gidx];
    const int gs   = offsets[gidx];
    const int gend = (gidx + 1 < Btot) ? offsets[gidx + 1] : totG;
    const int cnt  = gend - gs;
    const float inv = 1.0f / (float)(cnt > 0 ? cnt : 1);

    // ---- pass 1: GMF ----
    {
        f32x4 gg = {0.f, 0.f, 0.f, 0.f};
        for (int i = gs; i < gend; ++i) {
            const int g = genre_ids[i];
            gg += ld4(ge_gmf + (size_t)g * 32 + 4 * c);
        }
        const float* ugp = ue_gmf + (size_t)u * 96 + 4 * c;
        const float* mgp = me_gmf + (size_t)mv * 64 + 4 * c;
        f32x4 ug0 = ld4(ugp), ug1 = ld4(ugp + 32), ug2 = ld4(ugp + 64);
        f32x4 mg0 = ld4(mgp), mg1 = ld4(mgp + 32);
        const float* wop = w_out + 4 * c;
        f32x4 wo0 = ld4(wop), wo1 = ld4(wop + 32), wo2 = ld4(wop + 64);
        const float um = user_mem_w[u];
        const float mm = movie_mem_w[mv];

        float s = 0.f;
        #pragma unroll
        for (int q = 0; q < 4; ++q)
            s += ug0[q]*mg0[q]*wo0[q] + ug1[q]*mg1[q]*wo1[q] + ug2[q]*(gg[q]*inv)*wo2[q];
        if (c == 0) s += um + mm + b_out[0];
        s += __shfl_xor(s, 1);
        s += __shfl_xor(s, 2);
        s += __shfl_xor(s, 4);
        if (c == 0) pv[gidx] = s;
    }

    // ---- pass 2: MLP input row -> X (bf16) ----
    {
        f32x4 gm = {0.f, 0.f, 0.f, 0.f};
        for (int i = gs; i < gend; ++i) {
            const int g = genre_ids[i];
            gm += ld4(ge_mlp + (size_t)g * 32 + 4 * c);
        }
        const float* up = ue_mlp + (size_t)u * 96 + 12 * c;
        const float* mp = me_mlp + (size_t)mv * 64 + 8 * c;
        f32x4 ua0 = ld4(up), ua1 = ld4(up + 4), ua2 = ld4(up + 8);
        f32x4 ma0 = ld4(mp), ma1 = ld4(mp + 4);

        __bf16* xr = X + (size_t)gidx * 192;
        bf16x4 t;
        t[0]=f2bf(ua0[0]); t[1]=f2bf(ua0[1]); t[2]=f2bf(ua0[2]); t[3]=f2bf(ua0[3]);
        *(bf16x4*)(xr + 12 * c)      = t;
        t[0]=f2bf(ua1[0]); t[1]=f2bf(ua1[1]); t[2]=f2bf(ua1[2]); t[3]=f2bf(ua1[3]);
        *(bf16x4*)(xr + 12 * c + 4)  = t;
        t[0]=f2bf(ua2[0]); t[1]=f2bf(ua2[1]); t[2]=f2bf(ua2[2]); t[3]=f2bf(ua2[3]);
        *(bf16x4*)(xr + 12 * c + 8)  = t;
        t[0]=f2bf(ma0[0]); t[1]=f2bf(ma0[1]); t[2]=f2bf(ma0[2]); t[3]=f2bf(ma0[3]);
        *(bf16x4*)(xr + 96 + 8 * c)  = t;
        t[0]=f2bf(ma1[0]); t[1]=f2bf(ma1[1]); t[2]=f2bf(ma1[2]); t[3]=f2bf(ma1[3]);
        *(bf16x4*)(xr + 96 + 8 * c + 4) = t;
        t[0]=f2bf(gm[0]*inv); t[1]=f2bf(gm[1]*inv); t[2]=f2bf(gm[2]*inv); t[3]=f2bf(gm[3]*inv);
        *(bf16x4*)(xr + 160 + 4 * c) = t;
    }
}

// =================== Kernel B: MLP via MFMA + epilogue ===================
__global__ __launch_bounds__(256, 4)
void ncf_mlp(const __bf16* __restrict__ X, const float* __restrict__ pv,
             const __bf16* __restrict__ wbf,
             const float* __restrict__ b1, const float* __restrict__ b2,
             const float* __restrict__ w_out,
             float* __restrict__ out, int Btot)
{
    __shared__ __bf16 Hs[64 * 72];

    const int tid  = threadIdx.x;
    const int lane = tid & 63;
    const int wid  = tid >> 6;
    const int lr   = lane & 15;
    const int lg   = lane >> 4;
    const int e0   = blockIdx.x * 64;

    const int row = min(e0 + wid * 16 + lr, Btot - 1);

    // A-fragments straight from X
    const __bf16* xr = X + (size_t)row * 192 + lg * 8;
    bf16x8 fr[6];
    #pragma unroll
    for (int kt = 0; kt < 6; ++kt)
        fr[kt] = *(const bf16x8*)(xr + kt * 32);

    // GEMM1
    const __bf16* w1bf = wbf;
    f32x4 acc1[4] = {};
    #pragma unroll
    for (int kt = 0; kt < 6; ++kt) {
        #pragma unroll
        for (int nt = 0; nt < 4; ++nt) {
            bf16x8 bw = *(const bf16x8*)(w1bf + (size_t)(nt * 16 + lr) * 192 + kt * 32 + lg * 8);
            acc1[nt] = __builtin_amdgcn_mfma_f32_16x16x32_bf16(fr[kt], bw, acc1[nt], 0, 0, 0);
        }
    }
    #pragma unroll
    for (int nt = 0; nt < 4; ++nt) {
        const float bv = b1[nt * 16 + lr];
        #pragma unroll
        for (int r = 0; r < 4; ++r) {
            float v = acc1[nt][r] + bv;
            v = v > 0.f ? v : 0.f;
            Hs[(wid * 16 + lg * 4 + r) * 72 + nt * 16 + lr] = f2bf(v);
        }
    }
    __syncthreads();

    // GEMM2 + epilogue
    const __bf16* w2bf = wbf + 12288;
    f32x4 acc2[6] = {};
    #pragma unroll
    for (int kt = 0; kt < 2; ++kt) {
        bf16x8 av = *(const bf16x8*)&Hs[(wid * 16 + lr) * 72 + kt * 32 + lg * 8];
        #pragma unroll
        for (int nt = 0; nt < 6; ++nt) {
            bf16x8 bw = *(const bf16x8*)(w2bf + (size_t)(nt * 16 + lr) * 64 + kt * 32 + lg * 8);
            acc2[nt] = __builtin_amdgcn_mfma_f32_16x16x32_bf16(av, bw, acc2[nt], 0, 0, 0);
        }
    }

    float s0 = 0.f, s1 = 0.f, s2 = 0.f, s3 = 0.f;
    #pragma unroll
    for (int nt = 0; nt < 6; ++nt) {
        const int col = nt * 16 + lr;
        const float b2v = b2[col];
        const float wo  = w_out[96 + col];
        float v;
        v = acc2[nt][0] + b2v; v = v > 0.f ? v : 0.f; s0 += v * wo;
        v = acc2[nt][1] + b2v; v = v > 0.f ? v : 0.f; s1 += v * wo;
        v = acc2[nt][2] + b2v; v = v > 0.f ? v : 0.f; s2 += v * wo;
        v = acc2[nt][3] + b2v; v = v > 0.f ? v : 0.f; s3 += v * wo;
    }
    #pragma unroll
    for (int mask = 1; mask <= 8; mask <<= 1) {
        s0 += __shfl_xor(s0, mask);
        s1 += __shfl_xor(s1, mask);
        s2 += __shfl_xor(s2, mask);
        s3 += __shfl_xor(s3, mask);
    }

    if (lr == 0) {
        const int rowb = e0 + wid * 16 + lg * 4;
        if (rowb + 0 < Btot) out[rowb + 0] = pv[rowb + 0] + s0;
        if (rowb + 1 < Btot) out[rowb + 1] = pv[rowb + 1] + s1;
        if (rowb + 2 < Btot) out[rowb + 2] = pv[rowb + 2] + s2;
        if (rowb + 3 < Btot) out[rowb + 3] = pv[rowb + 3] + s3;
    }
}

extern "C" void kernel_launch(void* const* d_in, const int* in_sizes, int n_in,
                              void* d_out, int out_size, void* d_ws, size_t ws_size,
                              hipStream_t stream) {
    const int*   user_ids    = (const int*)d_in[0];
    const int*   movie_ids   = (const int*)d_in[1];
    const int*   genre_ids   = (const int*)d_in[2];
    const int*   offsets     = (const int*)d_in[3];
    const float* user_mem_w  = (const float*)d_in[4];
    const float* movie_mem_w = (const float*)d_in[5];
    const float* ue_gmf      = (const float*)d_in[6];
    const float* me_gmf      = (const float*)d_in[7];
    const float* ge_gmf      = (const float*)d_in[8];
    const float* ue_mlp      = (const float*)d_in[9];
    const float* me_mlp      = (const float*)d_in[10];
    const float* ge_mlp      = (const float*)d_in[11];
    const float* w1          = (const float*)d_in[12];
    const float* b1          = (const float*)d_in[13];
    const float* w2          = (const float*)d_in[14];
    const float* b2          = (const float*)d_in[15];
    const float* w_out       = (const float*)d_in[16];
    const float* b_out       = (const float*)d_in[17];

    const int Btot = in_sizes[0];
    const int totG = in_sizes[2];

    char* ws = (char*)d_ws;
    __bf16* wbf = (__bf16*)ws;
    __bf16* X   = (__bf16*)(ws + X_OFF_BYTES);
    float*  pvb = (float*)(ws + X_OFF_BYTES + (size_t)Btot * 192 * 2);

    prep_weights<<<72, 256, 0, stream>>>(w1, w2, wbf);

    const int gridA = (Btot + AT - 1) / AT;
    // Launched TWICE on purpose (idempotent): dur_r5 - dur_r4 == steady-state
    // gather-kernel cost. Diagnostic round.
    ncf_gather<<<gridA, 256, 0, stream>>>(
        user_ids, movie_ids, genre_ids, offsets,
        user_mem_w, movie_mem_w,
        ue_gmf, me_gmf, ge_gmf,
        ue_mlp, me_mlp, ge_mlp,
        w_out, b_out, X, pvb, Btot, totG);
    ncf_gather<<<gridA, 256, 0, stream>>>(
        user_ids, movie_ids, genre_ids, offsets,
        user_mem_w, movie_mem_w,
        ue_gmf, me_gmf, ge_gmf,
        ue_mlp, me_mlp, ge_mlp,
        w_out, b_out, X, pvb, Btot, totG);

    const int gridB = (Btot + 63) / 64;
    ncf_mlp<<<gridB, 256, 0, stream>>>(
        X, pvb, wbf, b1, b2, w_out, (float*)d_out, Btot);
}

// Round 6
// 29.834 us; speedup vs baseline: 2.3835x; 2.3835x over previous
//
#include <hip/hip_runtime.h>

#define BT 64
#define NTHREADS 256

typedef __attribute__((ext_vector_type(8))) __bf16 bf16x8;
typedef __attribute__((ext_vector_type(4))) __bf16 bf16x4;
typedef __attribute__((ext_vector_type(4))) float f32x4;

__device__ __forceinline__ __bf16 f2bf(float f) { return (__bf16)f; }
__device__ __forceinline__ f32x4 ld4(const float* p) { return *(const f32x4*)p; }

// Single fused kernel. Per-block: convert W1/W2 f32->bf16 into padded LDS,
// register-gather embeddings, GMF dot, MFMA MLP, fused epilogue.
// LDS: W1 [64][200] + W2 [96][72] + Hs [64][72] = 48640 B -> 3 blocks/CU.
__global__ __launch_bounds__(NTHREADS, 3)
void ncf_one(const int* __restrict__ user_ids, const int* __restrict__ movie_ids,
             const int* __restrict__ genre_ids, const int* __restrict__ offsets,
             const float* __restrict__ user_mem_w, const float* __restrict__ movie_mem_w,
             const float* __restrict__ ue_gmf, const float* __restrict__ me_gmf,
             const float* __restrict__ ge_gmf,
             const float* __restrict__ ue_mlp, const float* __restrict__ me_mlp,
             const float* __restrict__ ge_mlp,
             const float* __restrict__ w1, const float* __restrict__ b1,
             const float* __restrict__ w2, const float* __restrict__ b2,
             const float* __restrict__ w_out, const float* __restrict__ b_out,
             float* __restrict__ out, int Btot, int totG)
{
    __shared__ __bf16 WL1[64 * 200];   // row stride 400 B (bank stride 4 -> 2-way max)
    __shared__ __bf16 WL2[96 * 72];    // row stride 144 B
    __shared__ __bf16 Hs[64 * 72];

    const int tid  = threadIdx.x;
    const int lane = tid & 63;
    const int wid  = tid >> 6;
    const int lr   = lane & 15;
    const int lg   = lane >> 4;
    const int e0   = blockIdx.x * BT;

    // ---- weight convert into LDS (L2-hot broadcast reads) ----
    #pragma unroll
    for (int j = 0; j < 12; ++j) {               // w1: 3072 f32x4, rows of 48
        const int v = tid + j * 256;
        const int r = v / 48, c4 = v % 48;
        f32x4 a = ld4(w1 + (size_t)v * 4);
        bf16x4 t; t[0]=f2bf(a[0]); t[1]=f2bf(a[1]); t[2]=f2bf(a[2]); t[3]=f2bf(a[3]);
        *(bf16x4*)&WL1[r * 200 + c4 * 4] = t;
    }
    #pragma unroll
    for (int j = 0; j < 6; ++j) {                // w2: 1536 f32x4, rows of 16
        const int v = tid + j * 256;
        const int r = v >> 4, c4 = v & 15;
        f32x4 a = ld4(w2 + (size_t)v * 4);
        bf16x4 t; t[0]=f2bf(a[0]); t[1]=f2bf(a[1]); t[2]=f2bf(a[2]); t[3]=f2bf(a[3]);
        *(bf16x4*)&WL2[r * 72 + c4 * 4] = t;
    }

    // ---- per-element gather (4 lanes/element) ----
    const int erow = wid * 16 + lr;
    const int gidx = min(e0 + erow, Btot - 1);
    const int u    = user_ids[gidx];
    const int mv   = movie_ids[gidx];
    const int gs   = offsets[gidx];
    const int gend = (gidx + 1 < Btot) ? offsets[gidx + 1] : totG;
    const int cnt  = gend - gs;
    const float inv = 1.0f / (float)(cnt > 0 ? cnt : 1);

    // single genre pass: gmf chunks gg0/gg1, mlp chunks gm0/gm1
    f32x4 gg0 = {0.f,0.f,0.f,0.f}, gg1 = {0.f,0.f,0.f,0.f};
    f32x4 gm0 = {0.f,0.f,0.f,0.f}, gm1 = {0.f,0.f,0.f,0.f};
    for (int i = gs; i < gend; ++i) {
        const int g = genre_ids[i];
        const float* pg = ge_gmf + (size_t)g * 32 + 4 * lg;
        gg0 += ld4(pg);
        gg1 += ld4(pg + 16);
        const float* pm = ge_mlp + (size_t)g * 32 + 8 * lg;
        gm0 += ld4(pm);
        gm1 += ld4(pm + 4);
    }

    // A-fragments: lane (lr,lg) holds X[erow][kt*32 + lg*8 .. +7]
    bf16x8 fr[6];
    {
        const float* up = ue_mlp + (size_t)u * 96 + lg * 8;
        const float* mp = me_mlp + (size_t)mv * 64 + lg * 8;
        #pragma unroll
        for (int kt = 0; kt < 3; ++kt) {
            f32x4 a = ld4(up + kt * 32), b = ld4(up + kt * 32 + 4);
            bf16x8 t;
            t[0]=f2bf(a[0]); t[1]=f2bf(a[1]); t[2]=f2bf(a[2]); t[3]=f2bf(a[3]);
            t[4]=f2bf(b[0]); t[5]=f2bf(b[1]); t[6]=f2bf(b[2]); t[7]=f2bf(b[3]);
            fr[kt] = t;
        }
        #pragma unroll
        for (int kt = 0; kt < 2; ++kt) {
            f32x4 a = ld4(mp + kt * 32), b = ld4(mp + kt * 32 + 4);
            bf16x8 t;
            t[0]=f2bf(a[0]); t[1]=f2bf(a[1]); t[2]=f2bf(a[2]); t[3]=f2bf(a[3]);
            t[4]=f2bf(b[0]); t[5]=f2bf(b[1]); t[6]=f2bf(b[2]); t[7]=f2bf(b[3]);
            fr[3 + kt] = t;
        }
        bf16x8 t;
        t[0]=f2bf(gm0[0]*inv); t[1]=f2bf(gm0[1]*inv); t[2]=f2bf(gm0[2]*inv); t[3]=f2bf(gm0[3]*inv);
        t[4]=f2bf(gm1[0]*inv); t[5]=f2bf(gm1[1]*inv); t[6]=f2bf(gm1[2]*inv); t[7]=f2bf(gm1[3]*inv);
        fr[5] = t;
    }

    // GMF dot (f32 exact)
    float pval;
    {
        float s = 0.f;
        #pragma unroll
        for (int j = 0; j < 4; ++j) {
            const int d = 4 * lg + 16 * j;
            f32x4 ug = ld4(ue_gmf + (size_t)u * 96 + d);
            f32x4 mg = ld4(me_gmf + (size_t)mv * 64 + d);
            f32x4 wo = ld4(w_out + d);
            s += ug[0]*mg[0]*wo[0] + ug[1]*mg[1]*wo[1] + ug[2]*mg[2]*wo[2] + ug[3]*mg[3]*wo[3];
        }
        {
            const int d = 64 + 4 * lg;
            f32x4 ug = ld4(ue_gmf + (size_t)u * 96 + d);
            f32x4 wo = ld4(w_out + d);
            s += ug[0]*gg0[0]*inv*wo[0] + ug[1]*gg0[1]*inv*wo[1]
               + ug[2]*gg0[2]*inv*wo[2] + ug[3]*gg0[3]*inv*wo[3];
        }
        {
            const int d = 80 + 4 * lg;
            f32x4 ug = ld4(ue_gmf + (size_t)u * 96 + d);
            f32x4 wo = ld4(w_out + d);
            s += ug[0]*gg1[0]*inv*wo[0] + ug[1]*gg1[1]*inv*wo[1]
               + ug[2]*gg1[2]*inv*wo[2] + ug[3]*gg1[3]*inv*wo[3];
        }
        if (lg == 0) s += user_mem_w[u] + movie_mem_w[mv] + b_out[0];
        s += __shfl_xor(s, 16);
        s += __shfl_xor(s, 32);
        pval = s;
    }

    __syncthreads();   // WL1/WL2 ready

    // ---- GEMM1: X[64x192] @ W1^T -> H[64x64] ----
    f32x4 acc1[4] = {};
    #pragma unroll
    for (int kt = 0; kt < 6; ++kt) {
        #pragma unroll
        for (int nt = 0; nt < 4; ++nt) {
            bf16x8 bw = *(const bf16x8*)&WL1[(nt * 16 + lr) * 200 + kt * 32 + lg * 8];
            acc1[nt] = __builtin_amdgcn_mfma_f32_16x16x32_bf16(fr[kt], bw, acc1[nt], 0, 0, 0);
        }
    }
    #pragma unroll
    for (int nt = 0; nt < 4; ++nt) {
        const float bv = b1[nt * 16 + lr];
        #pragma unroll
        for (int r = 0; r < 4; ++r) {
            float v = acc1[nt][r] + bv;
            v = v > 0.f ? v : 0.f;
            Hs[(wid * 16 + lg * 4 + r) * 72 + nt * 16 + lr] = f2bf(v);
        }
    }
    __syncthreads();

    // ---- GEMM2: H[64x64] @ W2^T -> [64x96], fused epilogue ----
    f32x4 acc2[6] = {};
    #pragma unroll
    for (int kt = 0; kt < 2; ++kt) {
        bf16x8 av = *(const bf16x8*)&Hs[(wid * 16 + lr) * 72 + kt * 32 + lg * 8];
        #pragma unroll
        for (int nt = 0; nt < 6; ++nt) {
            bf16x8 bw = *(const bf16x8*)&WL2[(nt * 16 + lr) * 72 + kt * 32 + lg * 8];
            acc2[nt] = __builtin_amdgcn_mfma_f32_16x16x32_bf16(av, bw, acc2[nt], 0, 0, 0);
        }
    }

    float s0 = 0.f, s1 = 0.f, s2 = 0.f, s3 = 0.f;
    #pragma unroll
    for (int nt = 0; nt < 6; ++nt) {
        const int col = nt * 16 + lr;
        const float b2v = b2[col];
        const float wo  = w_out[96 + col];
        float v;
        v = acc2[nt][0] + b2v; v = v > 0.f ? v : 0.f; s0 += v * wo;
        v = acc2[nt][1] + b2v; v = v > 0.f ? v : 0.f; s1 += v * wo;
        v = acc2[nt][2] + b2v; v = v > 0.f ? v : 0.f; s2 += v * wo;
        v = acc2[nt][3] + b2v; v = v > 0.f ? v : 0.f; s3 += v * wo;
    }
    #pragma unroll
    for (int mask = 1; mask <= 8; mask <<= 1) {
        s0 += __shfl_xor(s0, mask);
        s1 += __shfl_xor(s1, mask);
        s2 += __shfl_xor(s2, mask);
        s3 += __shfl_xor(s3, mask);
    }
    const float p0 = __shfl(pval, lg * 4 + 0);
    const float p1 = __shfl(pval, lg * 4 + 1);
    const float p2 = __shfl(pval, lg * 4 + 2);
    const float p3 = __shfl(pval, lg * 4 + 3);

    if (lr == 0) {
        const int rowb = e0 + wid * 16 + lg * 4;
        if (rowb + 0 < Btot) out[rowb + 0] = p0 + s0;
        if (rowb + 1 < Btot) out[rowb + 1] = p1 + s1;
        if (rowb + 2 < Btot) out[rowb + 2] = p2 + s2;
        if (rowb + 3 < Btot) out[rowb + 3] = p3 + s3;
    }
}

extern "C" void kernel_launch(void* const* d_in, const int* in_sizes, int n_in,
                              void* d_out, int out_size, void* d_ws, size_t ws_size,
                              hipStream_t stream) {
    const int*   user_ids    = (const int*)d_in[0];
    const int*   movie_ids   = (const int*)d_in[1];
    const int*   genre_ids   = (const int*)d_in[2];
    const int*   offsets     = (const int*)d_in[3];
    const float* user_mem_w  = (const float*)d_in[4];
    const float* movie_mem_w = (const float*)d_in[5];
    const float* ue_gmf      = (const float*)d_in[6];
    const float* me_gmf      = (const float*)d_in[7];
    const float* ge_gmf      = (const float*)d_in[8];
    const float* ue_mlp      = (const float*)d_in[9];
    const float* me_mlp      = (const float*)d_in[10];
    const float* ge_mlp      = (const float*)d_in[11];
    const float* w1          = (const float*)d_in[12];
    const float* b1          = (const float*)d_in[13];
    const float* w2          = (const float*)d_in[14];
    const float* b2          = (const float*)d_in[15];
    const float* w_out       = (const float*)d_in[16];
    const float* b_out       = (const float*)d_in[17];

    const int Btot = in_sizes[0];
    const int totG = in_sizes[2];

    const int grid = (Btot + BT - 1) / BT;
    ncf_one<<<grid, NTHREADS, 0, stream>>>(
        user_ids, movie_ids, genre_ids, offsets,
        user_mem_w, movie_mem_w,
        ue_gmf, me_gmf, ge_gmf,
        ue_mlp, me_mlp, ge_mlp,
        w1, b1, w2, b2, w_out, b_out,
        (float*)d_out, Btot, totG);
}